// Round 9
// baseline (240.475 us; speedup 1.0000x reference)
//
#include <hip/hip_runtime.h>
#include <hip/hip_bf16.h>

#define ACT 14
#define CC 128
#define HH 256
#define EPB 182                 // edges per batch (14*13)
#define NB 2048
#define M2 (NB*EPB)             // 372736 edge-rows
#define NS 520                  // nodeL stride in shorts
#define LP_CONST (-182.0f * 0.91893853320467274f)   // -E*0.5*ln(2pi)

typedef short s16x8 __attribute__((ext_vector_type(8)));
typedef float f32x4 __attribute__((ext_vector_type(4)));
typedef float f32x16 __attribute__((ext_vector_type(16)));

__device__ __forceinline__ short f2bf(float f) {
    unsigned u = __float_as_uint(f);
    unsigned r = (u + 0x7fffu + ((u >> 16) & 1u)) >> 16;   // RNE
    return (short)r;
}
__device__ __forceinline__ float b2f(short s) {
    return __uint_as_float(((unsigned)(unsigned short)s) << 16);
}
__device__ __forceinline__ float bflo(int m) { return __uint_as_float(((unsigned)m) << 16); }
__device__ __forceinline__ float bfhi(int m) { return __uint_as_float((unsigned)m & 0xffff0000u); }
__device__ __forceinline__ float leaky(float x) { return fmaxf(x, 0.01f * x); }
__device__ __forceinline__ float softplusf(float x) { return x > 15.f ? x : log1pf(expf(x)); }

union bf2u { __hip_bfloat162 h; int i; };
__device__ __forceinline__ int pk_bf16(float a, float b) {
    bf2u u; u.h = __float22bfloat162_rn(make_float2(a, b));
    return u.i;
}

// ---------------------------------------------------------------------------
// prep: one-time weight conversions (256 blocks x 256)
// ---------------------------------------------------------------------------
__global__ __launch_bounds__(256) void prep_kernel(
    const float* __restrict__ conv_w, const float* __restrict__ lin1_w,
    const float* __restrict__ lin2_w, const float* __restrict__ mu_w,
    const float* __restrict__ sig_w, const float* __restrict__ lin2_b,
    short* __restrict__ W2bf, short* __restrict__ W1bf,
    short* __restrict__ cwTbf, short* __restrict__ w1sTbf,
    int* __restrict__ msbf, int* __restrict__ b2p)
{
    int i = blockIdx.x * 256 + threadIdx.x;
    W2bf[i] = f2bf(lin2_w[i]);
    {
        int n = i >> 7, k = i & 127;
        float v = (n < 256) ? lin1_w[n * 256 + k] : lin1_w[(n - 256) * 256 + 128 + k];
        W1bf[i] = f2bf(v);
    }
    if (i < 16384) {
        int k = i >> 7, j = i & 127;
        cwTbf[i] = f2bf(conv_w[j * 128 + k]);
    }
    if (i < 32768) {
        int k = i >> 8, h = i & 255;
        w1sTbf[i] = f2bf(lin1_w[h * 256 + k] + lin1_w[h * 256 + 128 + k]);
    }
    if (i < 256) msbf[i] = pk_bf16(mu_w[i], sig_w[i]);
    if (i < 128) b2p[i] = pk_bf16(lin2_b[2 * i], lin2_b[2 * i + 1]);
}

// ---------------------------------------------------------------------------
// actor: TWO batches per block (1024 blocks), 512 threads = 8 waves.
//  A : stage state bf16 (aliased into h1L); ssum.
//  A2: g (2-way k-split, 2 accums) then w (1 out/thread, 4 accums).
//  B : node GEMM -> nodeL[2] (u+w | v), 16x16x32 MFMA.
//  C : 12 edge-tiles of 32; cooperative H1 build into frag-order
//      double-buffered LDS; W2 32-row strip/wave in VGPRs; 32x32x16 MFMA;
//      in-lane mu/sig epilogue with REGISTER tables (no LDS lookups).
// ---------------------------------------------------------------------------
__global__ __launch_bounds__(512, 4) void actor_kernel(
    const float* __restrict__ state, const short* __restrict__ W1bf,
    const short* __restrict__ W2bf,
    const short* __restrict__ cwTbf, const float* __restrict__ conv_b,
    const short* __restrict__ w1sTbf, const float* __restrict__ lin1_b,
    const int* __restrict__ b2p, const int* __restrict__ msbf,
    const float* __restrict__ mu_b, const float* __restrict__ sig_b,
    const float* __restrict__ noise, const int* __restrict__ edges,
    float* __restrict__ out)
{
    __shared__ short h1L[2][8192];           // 32 KB; [0] front aliased below
    __shared__ short nodeL[2 * ACT * NS];    // 29120 B
    __shared__ float ssumL[2][128];
    __shared__ float gL[2][128];
    __shared__ float wL[2][256];
    __shared__ float mu_acc[384], sg_acc[384];
    __shared__ float lp_acc[2];

    short* stateL = &h1L[0][0];              // 2*2560 shorts (dead before build)
    float* pp     = (float*)&h1L[0][5120];   // 512 f32 partials (dead before build)

    const int t = threadIdx.x, b = blockIdx.x;
    const int lane = t & 63, ln = lane & 15, q = lane >> 4;
    const int w = t >> 6;                     // wave 0..7
    const int l32 = lane & 31, hf = lane >> 5;

    // ---- phase A ----
    #pragma unroll
    for (int it = 0; it < 2; ++it) {
        int idx = it * 512 + t;
        int bt = idx >> 9, row = (idx >> 5) & 15, c4 = idx & 31;
        int kk = c4 >> 3, k8 = (c4 & 7) * 4;
        int* dst = (int*)&stateL[bt * 2560 + kk * 640 + row * 40 + k8];
        if (row < ACT) {
            f32x4 x = *(const f32x4*)(state + ((size_t)(2 * b + bt) * ACT + row) * CC + c4 * 4);
            dst[0] = pk_bf16(x[0], x[1]); dst[1] = pk_bf16(x[2], x[3]);
        } else { dst[0] = 0; dst[1] = 0; }
    }
    if (t >= 256) {
        int i = t - 256, bt = i >> 7, c = i & 127;    // ssum, both batches
        const float* sp = state + (size_t)(2 * b + bt) * ACT * CC + c;
        float s = 0.f;
        #pragma unroll
        for (int r = 0; r < ACT; ++r) s += sp[r * CC];
        ssumL[bt][c] = s * (1.f / 14.f);
    }
    if (t < 384) { mu_acc[t] = 0.f; sg_acc[t] = 0.f; }
    if (t < 2) lp_acc[t] = 0.f;
    __syncthreads();

    // ---- phase A2: g (2-way k-split, 2 accumulators) ----
    {
        int bt = t >> 8, s = (t >> 7) & 1, j = t & 127;
        const float* ss = ssumL[bt];
        float a0 = 0.f, a1 = 0.f;
        #pragma unroll 4
        for (int kk = 0; kk < 64; kk += 2) {
            int k = s * 64 + kk;
            a0 += b2f(cwTbf[k * 128 + j]) * ss[k];
            a1 += b2f(cwTbf[(k + 1) * 128 + j]) * ss[k + 1];
        }
        pp[t] = a0 + a1;
    }
    __syncthreads();
    if (t < 256) {
        int bt = t >> 7, j = t & 127;
        float a = pp[bt * 256 + j] + pp[bt * 256 + 128 + j] + conv_b[j];
        gL[bt][j] = fmaxf(a, 0.f);
    }
    __syncthreads();
    // ---- w: one output per thread, 4 accumulators ----
    {
        int bt = t >> 8, h = t & 255;
        const float* gg = gL[bt];
        float a0 = 0.f, a1 = 0.f, a2 = 0.f, a3 = 0.f;
        #pragma unroll 2
        for (int k = 0; k < 128; k += 4) {
            a0 += b2f(w1sTbf[k * 256 + h]) * gg[k];
            a1 += b2f(w1sTbf[(k + 1) * 256 + h]) * gg[k + 1];
            a2 += b2f(w1sTbf[(k + 2) * 256 + h]) * gg[k + 2];
            a3 += b2f(w1sTbf[(k + 3) * 256 + h]) * gg[k + 3];
        }
        wL[bt][h] = (a0 + a1) + (a2 + a3) + lin1_b[h];
    }
    __syncthreads();

    // ---- phase B: node GEMM (u = W1L@x + w | v = W1R@x), both batches ----
    f32x4 zero4 = {0.f, 0.f, 0.f, 0.f};
    f32x4 nacc[2][4];
    #pragma unroll
    for (int bt = 0; bt < 2; ++bt) {
        nacc[bt][0] = zero4; nacc[bt][1] = zero4;
        nacc[bt][2] = zero4; nacc[bt][3] = zero4;
    }
    #pragma unroll
    for (int c = 0; c < 4; ++c) {
        s16x8 a80 = *(const s16x8*)&stateL[0 * 2560 + c * 640 + ln * 40 + q * 8];
        s16x8 a81 = *(const s16x8*)&stateL[1 * 2560 + c * 640 + ln * 40 + q * 8];
        #pragma unroll
        for (int i = 0; i < 4; ++i) {
            int ct = w + 8 * i;               // 0..31
            s16x8 b8 = *(const s16x8*)&W1bf[(size_t)(ct * 16 + ln) * CC + c * 32 + q * 8];
            nacc[0][i] = __builtin_amdgcn_mfma_f32_16x16x32_bf16(a80, b8, nacc[0][i], 0, 0, 0);
            nacc[1][i] = __builtin_amdgcn_mfma_f32_16x16x32_bf16(a81, b8, nacc[1][i], 0, 0, 0);
        }
    }
    #pragma unroll
    for (int bt = 0; bt < 2; ++bt)
        #pragma unroll
        for (int i = 0; i < 4; ++i) {
            int col = (w + 8 * i) * 16 + ln;
            float wadd = (col < HH) ? wL[bt][col] : 0.f;
            #pragma unroll
            for (int rg = 0; rg < 4; ++rg) {
                int node = q * 4 + rg;
                if (node < ACT) nodeL[(bt * ACT + node) * NS + col] = f2bf(nacc[bt][i][rg] + wadd);
            }
        }

    // ---- W2 strip (32 rows x K=256) into VGPRs + register epilogue tables ----
    s16x8 wa[16];
    #pragma unroll
    for (int c = 0; c < 16; ++c)
        wa[c] = *(const s16x8*)&W2bf[(size_t)(w * 32 + l32) * HH + c * 16 + hf * 8];
    int b2k[8], msk[16];
    {
        int ns = w * 32;
        #pragma unroll
        for (int a = 0; a < 4; ++a) {
            b2k[a * 2]     = b2p[(ns >> 1) + 4 * a + 2 * hf];
            b2k[a * 2 + 1] = b2p[(ns >> 1) + 4 * a + 2 * hf + 1];
        }
        #pragma unroll
        for (int r = 0; r < 16; ++r)
            msk[r] = msbf[ns + (r & 3) + 8 * (r >> 2) + 4 * hf];
    }
    __syncthreads();   // nodeL visible; stateL/pp now dead

    // cooperative H1 build (each element computed once), frag-order layout
    auto build = [&](int tile, int bufi) {
        int bt = (tile >= 6) ? 1 : 0;
        int e32 = t & 31;
        int e = (tile - bt * 6) * 32 + e32;
        bool ok = e < EPB;
        int base = bt * ACT * NS;
        int uo = base, vo = base + HH;
        if (ok) { int2 p = ((const int2*)edges)[e]; uo += p.x * NS; vo += p.y * NS; }
        int sl = t >> 5;                       // 0..15
        #pragma unroll
        for (int s = 0; s < 2; ++s) {
            int slot = sl + 16 * s;            // 0..31
            int chunk = slot >> 1, half = slot & 1;
            int koff = chunk * 16 + half * 8;
            int o[4] = {0, 0, 0, 0};
            if (ok) {
                s16x8 u8 = *(const s16x8*)&nodeL[uo + koff];
                s16x8 v8 = *(const s16x8*)&nodeL[vo + koff];
                const int* ui = (const int*)&u8;
                const int* vi = (const int*)&v8;
                #pragma unroll
                for (int j = 0; j < 4; ++j) {
                    int uu = ui[j], vv = vi[j];
                    float s0 = bflo(uu) + bflo(vv);
                    float s1 = bfhi(uu) + bfhi(vv);
                    o[j] = pk_bf16(leaky(s0), leaky(s1));
                }
            }
            *(s16x8*)&h1L[bufi][chunk * 512 + (half * 32 + e32) * 8] = *(const s16x8*)o;
        }
    };

    build(0, 0);
    for (int tile = 0; tile < 12; ++tile) {
        __syncthreads();
        if (tile < 11) build(tile + 1, (tile + 1) & 1);
        const int buf = tile & 1;
        f32x16 acc;
        #pragma unroll
        for (int r = 0; r < 16; ++r) acc[r] = 0.f;
        #pragma unroll
        for (int c = 0; c < 16; ++c) {
            s16x8 b8 = *(const s16x8*)&h1L[buf][c * 512 + lane * 8];
            acc = __builtin_amdgcn_mfma_f32_32x32x16_bf16(wa[c], b8, acc, 0, 0, 0);
        }
        // in-lane epilogue: lane&31 = edge; regs = 32 n-rows of this strip
        int bt = (tile >= 6) ? 1 : 0;
        int col0 = (tile - bt * 6) * 32;
        float pmu = 0.f, psg = 0.f;
        #pragma unroll
        for (int r = 0; r < 16; ++r) {
            int bpv = b2k[(r >> 2) * 2 + ((r & 3) >> 1)];
            float b2v = (r & 1) ? bfhi(bpv) : bflo(bpv);
            float h2 = leaky(acc[r] + b2v);
            int ms = msk[r];
            pmu += bflo(ms) * h2;
            psg += bfhi(ms) * h2;
        }
        pmu += __shfl_xor(pmu, 32);
        psg += __shfl_xor(psg, 32);
        if (lane < 32) {
            atomicAdd(&mu_acc[bt * 192 + col0 + l32], pmu);
            atomicAdd(&sg_acc[bt * 192 + col0 + l32], psg);
        }
    }
    __syncthreads();

    // ---- final head, both batches ----
    float lpv = 0.f;
    {
        int bt = t >> 8, i = t & 255;
        if (i < EPB) {
            float mu = softplusf(mu_acc[bt * 192 + i] + mu_b[0]);
            float sd = softplusf(sg_acc[bt * 192 + i] + sig_b[0]);
            float z = noise[(size_t)(2 * b + bt) * EPB + i];
            out[(size_t)(2 * b + bt) * EPB + i] = mu + sd * z;
            lpv = -0.5f * z * z - logf(sd);
        }
    }
    #pragma unroll
    for (int off = 1; off < 64; off <<= 1) lpv += __shfl_xor(lpv, off);
    if (lane == 0) atomicAdd(&lp_acc[t >> 8], lpv);
    __syncthreads();
    if (t < 2) out[M2 + 2 * b + t] = lp_acc[t] + LP_CONST;
}

// ---------------------------------------------------------------------------
extern "C" void kernel_launch(void* const* d_in, const int* in_sizes, int n_in,
                              void* d_out, int out_size, void* d_ws, size_t ws_size,
                              hipStream_t stream)
{
    const float* state  = (const float*)d_in[0];
    const float* conv_w = (const float*)d_in[1];
    const float* conv_b = (const float*)d_in[2];
    const float* lin1_w = (const float*)d_in[3];
    const float* lin1_b = (const float*)d_in[4];
    const float* lin2_w = (const float*)d_in[5];
    const float* lin2_b = (const float*)d_in[6];
    const float* mu_w   = (const float*)d_in[7];
    const float* mu_b   = (const float*)d_in[8];
    const float* sig_w  = (const float*)d_in[9];
    const float* sig_b  = (const float*)d_in[10];
    const float* noise  = (const float*)d_in[11];
    const int*   edges  = (const int*)d_in[13];
    float* out = (float*)d_out;

    char* ws = (char*)d_ws;
    short* W2bf   = (short*)ws;  ws += 65536 * 2;
    short* W1bf   = (short*)ws;  ws += 65536 * 2;
    short* cwTbf  = (short*)ws;  ws += 16384 * 2;
    short* w1sTbf = (short*)ws;  ws += 32768 * 2;
    int*   msbf   = (int*)ws;    ws += 256 * 4;
    int*   b2p    = (int*)ws;    ws += 128 * 4;

    prep_kernel<<<256, 256, 0, stream>>>(conv_w, lin1_w, lin2_w, mu_w, sig_w, lin2_b,
                                         W2bf, W1bf, cwTbf, w1sTbf, msbf, b2p);
    actor_kernel<<<NB / 2, 512, 0, stream>>>(state, W1bf, W2bf,
                                             cwTbf, conv_b, w1sTbf, lin1_b,
                                             b2p, msbf, mu_b, sig_b,
                                             noise, edges, out);
}

// Round 10
// 209.633 us; speedup vs baseline: 1.1471x; 1.1471x over previous
//
#include <hip/hip_runtime.h>
#include <hip/hip_bf16.h>

#define ACT 14
#define CC 128
#define HH 256
#define EPB 182                 // edges per batch (14*13)
#define NB 2048
#define M2 (NB*EPB)             // 372736 edge-rows
#define NS 520                  // nodeL stride in shorts
#define LP_CONST (-182.0f * 0.91893853320467274f)   // -E*0.5*ln(2pi)

typedef short s16x8 __attribute__((ext_vector_type(8)));
typedef float f32x4 __attribute__((ext_vector_type(4)));
typedef int   i32x4 __attribute__((ext_vector_type(4)));
typedef float f32x16 __attribute__((ext_vector_type(16)));

__device__ __forceinline__ short f2bf(float f) {
    unsigned u = __float_as_uint(f);
    unsigned r = (u + 0x7fffu + ((u >> 16) & 1u)) >> 16;   // RNE
    return (short)r;
}
__device__ __forceinline__ float b2f(short s) {
    return __uint_as_float(((unsigned)(unsigned short)s) << 16);
}
__device__ __forceinline__ float bflo(int m) { return __uint_as_float(((unsigned)m) << 16); }
__device__ __forceinline__ float bfhi(int m) { return __uint_as_float((unsigned)m & 0xffff0000u); }
__device__ __forceinline__ float leaky(float x) { return fmaxf(x, 0.01f * x); }
__device__ __forceinline__ float softplusf(float x) { return x > 15.f ? x : log1pf(expf(x)); }

union bf2u { __hip_bfloat162 h; int i; };
__device__ __forceinline__ int pk_bf16(float a, float b) {
    bf2u u; u.h = __float22bfloat162_rn(make_float2(a, b));
    return u.i;
}

// ---------------------------------------------------------------------------
// prep: one-time weight conversions (256 blocks x 256)
// ---------------------------------------------------------------------------
__global__ __launch_bounds__(256) void prep_kernel(
    const float* __restrict__ conv_w, const float* __restrict__ lin1_w,
    const float* __restrict__ lin2_w, const float* __restrict__ mu_w,
    const float* __restrict__ sig_w,
    short* __restrict__ W2bf, short* __restrict__ W1bf,
    short* __restrict__ cwTbf, short* __restrict__ w1sTbf,
    int* __restrict__ msbf)
{
    int i = blockIdx.x * 256 + threadIdx.x;
    W2bf[i] = f2bf(lin2_w[i]);
    {
        int n = i >> 7, k = i & 127;
        float v = (n < 256) ? lin1_w[n * 256 + k] : lin1_w[(n - 256) * 256 + 128 + k];
        W1bf[i] = f2bf(v);
    }
    if (i < 16384) {
        int k = i >> 7, j = i & 127;
        cwTbf[i] = f2bf(conv_w[j * 128 + k]);
    }
    if (i < 32768) {
        int k = i >> 8, h = i & 255;
        w1sTbf[i] = f2bf(lin1_w[h * 256 + k] + lin1_w[h * 256 + 128 + k]);
    }
    if (i < 256) msbf[i] = pk_bf16(mu_w[i], sig_w[i]);
}

// ---------------------------------------------------------------------------
// actor: TWO batches per block (1024 blocks), 512 threads = 8 waves.
//  A : stage state bf16 (aliased into h1L); ssum; LDS tables.
//  A2: g (2-way k-split, 2 accums) then w (1 out/thread, 4 accums).
//  B : node GEMM -> nodeL[2] (u+w | v), 16x16x32 MFMA.
//  C : 12 edge-tiles of 32; cooperative H1 build into frag-order
//      double-buffered LDS; W2 32-row strip/wave in VGPRs; 32x32x16 MFMA;
//      in-lane mu/sig epilogue with VECTORIZED LDS tables (4x b128 each).
// ---------------------------------------------------------------------------
__global__ __launch_bounds__(512, 4) void actor_kernel(
    const float* __restrict__ state, const short* __restrict__ W1bf,
    const short* __restrict__ W2bf,
    const short* __restrict__ cwTbf, const float* __restrict__ conv_b,
    const short* __restrict__ w1sTbf, const float* __restrict__ lin1_b,
    const float* __restrict__ lin2_b, const int* __restrict__ msbf,
    const float* __restrict__ mu_b, const float* __restrict__ sig_b,
    const float* __restrict__ noise, const int* __restrict__ edges,
    float* __restrict__ out)
{
    __shared__ short h1L[2][8192];           // 32 KB; [0] front aliased below
    __shared__ short nodeL[2 * ACT * NS];    // 29120 B
    __shared__ float ssumL[2][128];
    __shared__ float gL[2][128];
    __shared__ float wL[2][256];
    __shared__ float b2L[256];               // lin2_b, vector-readable
    __shared__ int   msL[256];               // packed (mu,sig) bf16 pairs
    __shared__ float mu_acc[384], sg_acc[384];
    __shared__ float lp_acc[2];

    short* stateL = &h1L[0][0];              // 2*2560 shorts (dead before build)
    float* pp     = (float*)&h1L[0][5120];   // 512 f32 partials (dead before build)

    const int t = threadIdx.x, b = blockIdx.x;
    const int lane = t & 63, ln = lane & 15, q = lane >> 4;
    const int w = t >> 6;                     // wave 0..7
    const int l32 = lane & 31, hf = lane >> 5;

    // ---- phase A ----
    #pragma unroll
    for (int it = 0; it < 2; ++it) {
        int idx = it * 512 + t;
        int bt = idx >> 9, row = (idx >> 5) & 15, c4 = idx & 31;
        int kk = c4 >> 3, k8 = (c4 & 7) * 4;
        int* dst = (int*)&stateL[bt * 2560 + kk * 640 + row * 40 + k8];
        if (row < ACT) {
            f32x4 x = *(const f32x4*)(state + ((size_t)(2 * b + bt) * ACT + row) * CC + c4 * 4);
            dst[0] = pk_bf16(x[0], x[1]); dst[1] = pk_bf16(x[2], x[3]);
        } else { dst[0] = 0; dst[1] = 0; }
    }
    if (t < 256) {
        b2L[t] = lin2_b[t];
        msL[t] = msbf[t];
    } else {
        int i = t - 256, bt = i >> 7, c = i & 127;    // ssum, both batches
        const float* sp = state + (size_t)(2 * b + bt) * ACT * CC + c;
        float s = 0.f;
        #pragma unroll
        for (int r = 0; r < ACT; ++r) s += sp[r * CC];
        ssumL[bt][c] = s * (1.f / 14.f);
    }
    if (t < 384) { mu_acc[t] = 0.f; sg_acc[t] = 0.f; }
    if (t < 2) lp_acc[t] = 0.f;
    __syncthreads();

    // ---- phase A2: g (2-way k-split, 2 accumulators) ----
    {
        int bt = t >> 8, s = (t >> 7) & 1, j = t & 127;
        const float* ss = ssumL[bt];
        float a0 = 0.f, a1 = 0.f;
        #pragma unroll 4
        for (int kk = 0; kk < 64; kk += 2) {
            int k = s * 64 + kk;
            a0 += b2f(cwTbf[k * 128 + j]) * ss[k];
            a1 += b2f(cwTbf[(k + 1) * 128 + j]) * ss[k + 1];
        }
        pp[t] = a0 + a1;
    }
    __syncthreads();
    if (t < 256) {
        int bt = t >> 7, j = t & 127;
        float a = pp[bt * 256 + j] + pp[bt * 256 + 128 + j] + conv_b[j];
        gL[bt][j] = fmaxf(a, 0.f);
    }
    __syncthreads();
    // ---- w: one output per thread, 4 accumulators ----
    {
        int bt = t >> 8, h = t & 255;
        const float* gg = gL[bt];
        float a0 = 0.f, a1 = 0.f, a2 = 0.f, a3 = 0.f;
        #pragma unroll 2
        for (int k = 0; k < 128; k += 4) {
            a0 += b2f(w1sTbf[k * 256 + h]) * gg[k];
            a1 += b2f(w1sTbf[(k + 1) * 256 + h]) * gg[k + 1];
            a2 += b2f(w1sTbf[(k + 2) * 256 + h]) * gg[k + 2];
            a3 += b2f(w1sTbf[(k + 3) * 256 + h]) * gg[k + 3];
        }
        wL[bt][h] = (a0 + a1) + (a2 + a3) + lin1_b[h];
    }
    __syncthreads();

    // ---- phase B: node GEMM (u = W1L@x + w | v = W1R@x), both batches ----
    f32x4 zero4 = {0.f, 0.f, 0.f, 0.f};
    f32x4 nacc[2][4];
    #pragma unroll
    for (int bt = 0; bt < 2; ++bt) {
        nacc[bt][0] = zero4; nacc[bt][1] = zero4;
        nacc[bt][2] = zero4; nacc[bt][3] = zero4;
    }
    #pragma unroll
    for (int c = 0; c < 4; ++c) {
        s16x8 a80 = *(const s16x8*)&stateL[0 * 2560 + c * 640 + ln * 40 + q * 8];
        s16x8 a81 = *(const s16x8*)&stateL[1 * 2560 + c * 640 + ln * 40 + q * 8];
        #pragma unroll
        for (int i = 0; i < 4; ++i) {
            int ct = w + 8 * i;               // 0..31
            s16x8 b8 = *(const s16x8*)&W1bf[(size_t)(ct * 16 + ln) * CC + c * 32 + q * 8];
            nacc[0][i] = __builtin_amdgcn_mfma_f32_16x16x32_bf16(a80, b8, nacc[0][i], 0, 0, 0);
            nacc[1][i] = __builtin_amdgcn_mfma_f32_16x16x32_bf16(a81, b8, nacc[1][i], 0, 0, 0);
        }
    }
    #pragma unroll
    for (int bt = 0; bt < 2; ++bt)
        #pragma unroll
        for (int i = 0; i < 4; ++i) {
            int col = (w + 8 * i) * 16 + ln;
            float wadd = (col < HH) ? wL[bt][col] : 0.f;
            #pragma unroll
            for (int rg = 0; rg < 4; ++rg) {
                int node = q * 4 + rg;
                if (node < ACT) nodeL[(bt * ACT + node) * NS + col] = f2bf(nacc[bt][i][rg] + wadd);
            }
        }

    // ---- W2 strip (32 rows x K=256) into VGPRs ----
    s16x8 wa[16];
    #pragma unroll
    for (int c = 0; c < 16; ++c)
        wa[c] = *(const s16x8*)&W2bf[(size_t)(w * 32 + l32) * HH + c * 16 + hf * 8];
    __syncthreads();   // nodeL visible; stateL/pp now dead

    // cooperative H1 build (each element computed once), frag-order layout
    auto build = [&](int tile, int bufi) {
        int bt = (tile >= 6) ? 1 : 0;
        int e32 = t & 31;
        int e = (tile - bt * 6) * 32 + e32;
        bool ok = e < EPB;
        int base = bt * ACT * NS;
        int uo = base, vo = base + HH;
        if (ok) { int2 p = ((const int2*)edges)[e]; uo += p.x * NS; vo += p.y * NS; }
        int sl = t >> 5;                       // 0..15
        #pragma unroll
        for (int s = 0; s < 2; ++s) {
            int slot = sl + 16 * s;            // 0..31
            int chunk = slot >> 1, half = slot & 1;
            int koff = chunk * 16 + half * 8;
            int o[4] = {0, 0, 0, 0};
            if (ok) {
                s16x8 u8 = *(const s16x8*)&nodeL[uo + koff];
                s16x8 v8 = *(const s16x8*)&nodeL[vo + koff];
                const int* ui = (const int*)&u8;
                const int* vi = (const int*)&v8;
                #pragma unroll
                for (int j = 0; j < 4; ++j) {
                    int uu = ui[j], vv = vi[j];
                    float s0 = bflo(uu) + bflo(vv);
                    float s1 = bfhi(uu) + bfhi(vv);
                    o[j] = pk_bf16(leaky(s0), leaky(s1));
                }
            }
            *(s16x8*)&h1L[bufi][chunk * 512 + (half * 32 + e32) * 8] = *(const s16x8*)o;
        }
    };

    build(0, 0);
    for (int tile = 0; tile < 12; ++tile) {
        __syncthreads();
        if (tile < 11) build(tile + 1, (tile + 1) & 1);
        const int buf = tile & 1;
        f32x16 acc;
        #pragma unroll
        for (int r = 0; r < 16; ++r) acc[r] = 0.f;
        #pragma unroll
        for (int c = 0; c < 16; ++c) {
            s16x8 b8 = *(const s16x8*)&h1L[buf][c * 512 + lane * 8];
            acc = __builtin_amdgcn_mfma_f32_32x32x16_bf16(wa[c], b8, acc, 0, 0, 0);
        }
        // in-lane epilogue: lane&31 = edge; regs r: n = w*32 + 4hf + 8g + i
        int bt = (tile >= 6) ? 1 : 0;
        int col0 = (tile - bt * 6) * 32;
        float pmu = 0.f, psg = 0.f;
        const int nsb = w * 32 + 4 * hf;
        #pragma unroll
        for (int g = 0; g < 4; ++g) {
            f32x4 b4 = *(const f32x4*)&b2L[nsb + 8 * g];     // 1x ds_read_b128
            i32x4 m4 = *(const i32x4*)&msL[nsb + 8 * g];     // 1x ds_read_b128
            #pragma unroll
            for (int i = 0; i < 4; ++i) {
                float h2 = leaky(acc[g * 4 + i] + b4[i]);
                pmu += bflo(m4[i]) * h2;
                psg += bfhi(m4[i]) * h2;
            }
        }
        pmu += __shfl_xor(pmu, 32);
        psg += __shfl_xor(psg, 32);
        if (lane < 32) {
            atomicAdd(&mu_acc[bt * 192 + col0 + l32], pmu);
            atomicAdd(&sg_acc[bt * 192 + col0 + l32], psg);
        }
    }
    __syncthreads();

    // ---- final head, both batches ----
    float lpv = 0.f;
    {
        int bt = t >> 8, i = t & 255;
        if (i < EPB) {
            float mu = softplusf(mu_acc[bt * 192 + i] + mu_b[0]);
            float sd = softplusf(sg_acc[bt * 192 + i] + sig_b[0]);
            float z = noise[(size_t)(2 * b + bt) * EPB + i];
            out[(size_t)(2 * b + bt) * EPB + i] = mu + sd * z;
            lpv = -0.5f * z * z - logf(sd);
        }
    }
    #pragma unroll
    for (int off = 1; off < 64; off <<= 1) lpv += __shfl_xor(lpv, off);
    if (lane == 0) atomicAdd(&lp_acc[t >> 8], lpv);
    __syncthreads();
    if (t < 2) out[M2 + 2 * b + t] = lp_acc[t] + LP_CONST;
}

// ---------------------------------------------------------------------------
extern "C" void kernel_launch(void* const* d_in, const int* in_sizes, int n_in,
                              void* d_out, int out_size, void* d_ws, size_t ws_size,
                              hipStream_t stream)
{
    const float* state  = (const float*)d_in[0];
    const float* conv_w = (const float*)d_in[1];
    const float* conv_b = (const float*)d_in[2];
    const float* lin1_w = (const float*)d_in[3];
    const float* lin1_b = (const float*)d_in[4];
    const float* lin2_w = (const float*)d_in[5];
    const float* lin2_b = (const float*)d_in[6];
    const float* mu_w   = (const float*)d_in[7];
    const float* mu_b   = (const float*)d_in[8];
    const float* sig_w  = (const float*)d_in[9];
    const float* sig_b  = (const float*)d_in[10];
    const float* noise  = (const float*)d_in[11];
    const int*   edges  = (const int*)d_in[13];
    float* out = (float*)d_out;

    char* ws = (char*)d_ws;
    short* W2bf   = (short*)ws;  ws += 65536 * 2;
    short* W1bf   = (short*)ws;  ws += 65536 * 2;
    short* cwTbf  = (short*)ws;  ws += 16384 * 2;
    short* w1sTbf = (short*)ws;  ws += 32768 * 2;
    int*   msbf   = (int*)ws;    ws += 256 * 4;

    prep_kernel<<<256, 256, 0, stream>>>(conv_w, lin1_w, lin2_w, mu_w, sig_w,
                                         W2bf, W1bf, cwTbf, w1sTbf, msbf);
    actor_kernel<<<NB / 2, 512, 0, stream>>>(state, W1bf, W2bf,
                                             cwTbf, conv_b, w1sTbf, lin1_b,
                                             lin2_b, msbf, mu_b, sig_b,
                                             noise, edges, out);
}